// Round 11
// baseline (344.899 us; speedup 1.0000x reference)
//
#include <hip/hip_runtime.h>
#include <math.h>

#define DIM 256
#define BATCH 16
#define NO 64
#define NI 512
#define NIP 528                     // padded Ek4 inner extent (8448 B hq-stride)
#define WFT_LD 272                  // padded WfT row stride (1088 B)
#define NEG_SLOPE 0.01f
#define CSCALE 2.885390081777927f   // 2*log2(e): tanh(x) = 1 - 2/(exp2(CSCALE*x)+1)
#define OT 2                        // o's per attn block
#define NBLK 512                    // grid size; all co-resident (2 blocks/CU)

typedef float f32x4 __attribute__((ext_vector_type(4)));
typedef __bf16 bf16x8 __attribute__((ext_vector_type(8)));
typedef unsigned int u32x4 __attribute__((ext_vector_type(4)));

__device__ __forceinline__ void split2(float f, unsigned int& hi16, float& lo) {
  unsigned int u = __builtin_bit_cast(unsigned int, f);
  unsigned int h = (u + 0x7FFFu + ((u >> 16) & 1u)) & 0xFFFF0000u; // RNE bf16
  hi16 = h >> 16;
  lo = f - __builtin_bit_cast(float, h);   // exact (Sterbenz)
}
__device__ __forceinline__ unsigned int rne16(float f) {
  unsigned int u = __builtin_bit_cast(unsigned int, f);
  return (u + 0x7FFFu + ((u >> 16) & 1u)) >> 16;
}
// agent-scope (sc1) store: write-through to the device coherence point so
// consumer blocks on other XCDs cannot see stale lines (per-XCD L2s are not
// coherent; producer-side fence lowering is not relied upon).
__device__ __forceinline__ void st_agent(float* p, float v) {
  __hip_atomic_store(p, v, __ATOMIC_RELAXED, __HIP_MEMORY_SCOPE_AGENT);
}
__device__ __forceinline__ void f4arr(float4 v, float* a) {
  a[0] = v.x; a[1] = v.y; a[2] = v.z; a[3] = v.w;
}

struct __align__(8) U2 { unsigned int x, y; };

// proj-phase LDS offsets (within the shared SMEM block)
#define OFF_AH 0
#define OFF_AL 9216
#define OFF_WH 18432
#define OFF_WL 27648
#define OFF_IDX 36864   // 64 ints
#define OFF_SWT 37120   // 8 ints

// ---------------------------------------------------------------------------
// One proj tile (512 threads, 8 waves of 32x16 wave-tiles on a 64x64 tile).
// L < 64: q tiles. 64 <= L < 576 (remapped): k tiles (mask-compacted,
// early-exit). L >= 576: Wf transpose. Block-uniform control flow throughout.
// ---------------------------------------------------------------------------
__device__ void proj_tile(
    int L, char* SMEM, int t, int lane, int wid,
    const float* __restrict__ q, const float* __restrict__ k,
    const float* __restrict__ W1, const float* __restrict__ b1,
    const float* __restrict__ Wf, const int* __restrict__ mask,
    float* __restrict__ Eq, float* __restrict__ Ek4, float* __restrict__ WfT)
{
  if (L >= 576) {                    // ---- Wf transpose (512 threads) ----
    float* smem = (float*)SMEM;
    const int tt = L - 576;
    const int tr = tt >> 2, tc = tt & 3;
#pragma unroll
    for (int p = 0; p < 2; ++p) {
      int idx2 = p * 512 + t;
      int row = idx2 >> 4, j = idx2 & 15;
      float4 vv = *(const float4*)(Wf + (size_t)(tr * 64 + row) * 256 + tc * 64 + j * 4);
      *(float4*)&smem[row * 68 + j * 4] = vv;
    }
    __syncthreads();
#pragma unroll
    for (int p = 0; p < 2; ++p) {
      int idx2 = p * 512 + t;
      int row = idx2 >> 4, j = idx2 & 15;
      float* dst = WfT + (size_t)(tc * 64 + row) * WFT_LD + tr * 64 + j * 4;
      st_agent(dst + 0, smem[(j * 4 + 0) * 68 + row]);
      st_agent(dst + 1, smem[(j * 4 + 1) * 68 + row]);
      st_agent(dst + 2, smem[(j * 4 + 2) * 68 + row]);
      st_agent(dst + 3, smem[(j * 4 + 3) * 68 + row]);
    }
    return;
  }

  // tile-index remap: L<64 -> q; 64..511 -> k with ki%8!=7; 512..575 -> ki%8==7
  int mt, nt;
  if (L < 64) { mt = L >> 2; nt = L & 3; }
  else if (L < 512) {
    int L2 = L - 64;
    int kip = L2 >> 2;                       // 0..111
    int ki = (kip / 7) * 8 + (kip % 7);      // skip ki%8==7
    mt = 16 + ki; nt = L2 & 3;
  } else {
    int L2 = L - 512;                        // 0..63
    int ki = ((L2 >> 2) << 3) + 7;           // ki%8==7 (jb0=448, usually exits)
    mt = 16 + ki; nt = L2 & 3;
  }

  const int h0 = nt * 64;
  const bool isq = (mt < 16);
  const int srow = t >> 4;                   // 0..31 (rows srow, srow+32)
  const int sc4  = t & 15;
  const int m0w = (wid >> 2) * 32, n0w = (wid & 3) * 16;
  const int lr = lane & 15, lg = lane >> 4;

  int* idx_s = (int*)(SMEM + OFF_IDX);
  int* swt   = (int*)(SMEM + OFF_SWT);

  const float* src;
  int coff, bb = 0, jb0 = 0, cntb = 0;
  int rowg[2];

  if (isq) {
    src  = q + (size_t)(mt * 64) * DIM;
    coff = 0;
    rowg[0] = srow; rowg[1] = srow + 32;
  } else {
    const int ki = mt - 16;
    bb  = ki >> 3;
    jb0 = (ki & 7) * 64;
    // ---- mask scan: thread t <-> entry t (512 threads) ----
    const int unm = (mask[bb * NI + t] == 0) ? 1 : 0;
    unsigned long long bal = __ballot(unm);
    int my = __popcll(bal & ((1ull << lane) - 1ull));
    if (lane == 0) swt[wid] = __popcll(bal);
    if (t < 64) idx_s[t] = 0;
    __syncthreads();
    int woffv = 0;
#pragma unroll
    for (int w2 = 0; w2 < 8; ++w2) {
      int v_ = swt[w2];
      if (w2 < wid) woffv += v_;
      cntb += v_;
    }
    const int mp = unm ? (woffv + my) : -1;
    if (mp >= jb0 && mp < jb0 + 64) idx_s[mp - jb0] = t;
    __syncthreads();
    if (jb0 >= cntb) return;                 // block-uniform
    src  = k + (size_t)bb * NI * DIM;
    coff = DIM;
    rowg[0] = idx_s[srow]; rowg[1] = idx_s[srow + 32];
  }

  f32x4 acc[2] = {};
  float4 aR[2], wR[2];
#define LOADC(c0_)                                                              \
  _Pragma("unroll")                                                             \
  for (int p = 0; p < 2; ++p) {                                                 \
    aR[p] = *(const float4*)(src + (size_t)rowg[p] * DIM + (c0_) + sc4 * 4);    \
    wR[p] = *(const float4*)(W1 + (size_t)(h0 + srow + p * 32) * (2 * DIM) + coff + (c0_) + sc4 * 4); \
  }

  LOADC(0)

  for (int c = 0; c < 4; ++c) {
#pragma unroll
    for (int p = 0; p < 2; ++p) {
      int row = srow + p * 32;
      int boff = row * 144 + sc4 * 8;
      unsigned int h0_, h1_, h2_, h3_;
      float l0, l1, l2, l3;
      split2(aR[p].x, h0_, l0); split2(aR[p].y, h1_, l1);
      split2(aR[p].z, h2_, l2); split2(aR[p].w, h3_, l3);
      *(U2*)(SMEM + OFF_AH + boff) = { h0_ | (h1_ << 16), h2_ | (h3_ << 16) };
      *(U2*)(SMEM + OFF_AL + boff) = { rne16(l0) | (rne16(l1) << 16),
                                       rne16(l2) | (rne16(l3) << 16) };
      split2(wR[p].x, h0_, l0); split2(wR[p].y, h1_, l1);
      split2(wR[p].z, h2_, l2); split2(wR[p].w, h3_, l3);
      *(U2*)(SMEM + OFF_WH + boff) = { h0_ | (h1_ << 16), h2_ | (h3_ << 16) };
      *(U2*)(SMEM + OFF_WL + boff) = { rne16(l0) | (rne16(l1) << 16),
                                       rne16(l2) | (rne16(l3) << 16) };
    }
    __syncthreads();

    if (c < 3) { LOADC((c + 1) * 64) }

#pragma unroll
    for (int kk = 0; kk < 2; ++kk) {
      const int kb = kk * 64 + lg * 16;
      bf16x8 ah[2], al[2], bh, bl;
#pragma unroll
      for (int mi = 0; mi < 2; ++mi) {
        int row = m0w + mi * 16 + lr;
        ah[mi] = __builtin_bit_cast(bf16x8, *(const u32x4*)(SMEM + OFF_AH + row * 144 + kb));
        al[mi] = __builtin_bit_cast(bf16x8, *(const u32x4*)(SMEM + OFF_AL + row * 144 + kb));
      }
      {
        int row = n0w + lr;
        bh = __builtin_bit_cast(bf16x8, *(const u32x4*)(SMEM + OFF_WH + row * 144 + kb));
        bl = __builtin_bit_cast(bf16x8, *(const u32x4*)(SMEM + OFF_WL + row * 144 + kb));
      }
#pragma unroll
      for (int mi = 0; mi < 2; ++mi) {
        acc[mi] = __builtin_amdgcn_mfma_f32_16x16x32_bf16(ah[mi], bh, acc[mi], 0, 0, 0);
        acc[mi] = __builtin_amdgcn_mfma_f32_16x16x32_bf16(ah[mi], bl, acc[mi], 0, 0, 0);
        acc[mi] = __builtin_amdgcn_mfma_f32_16x16x32_bf16(al[mi], bh, acc[mi], 0, 0, 0);
      }
    }
    __syncthreads();
  }
#undef LOADC

  // epilogue (agent-scope stores). C/D layout: col(n)=lane&15, row=(lane>>4)*4+reg
  const int h = h0 + n0w + lr;
  if (isq) {
    const int r0 = mt * 64;
    float b1v = b1[h];
#pragma unroll
    for (int mi = 0; mi < 2; ++mi)
#pragma unroll
      for (int rg = 0; rg < 4; ++rg) {
        int r = r0 + m0w + mi * 16 + lg * 4 + rg;
        st_agent(Eq + (size_t)r * DIM + h,
                 __builtin_amdgcn_exp2f((acc[mi][rg] + b1v) * CSCALE));
      }
  } else {
    const int lim = cntb - jb0;
#pragma unroll
    for (int mi = 0; mi < 2; ++mi)
#pragma unroll
      for (int rg = 0; rg < 4; ++rg) {
        int local = m0w + mi * 16 + lg * 4 + rg;
        if (local < lim) {
          st_agent(Ek4 + ((size_t)(bb * 64 + (h >> 2)) * NIP + jb0 + local) * 4 + (h & 3),
                   __builtin_amdgcn_exp2f(acc[mi][rg] * CSCALE));
        }
      }
  }
}

// ---------------------------------------------------------------------------
// FUSED kernel, REGULAR launch (graph-capture-safe): phase A = proj (592
// tiles over 512 blocks; blocks 0..79 take a second, mostly-early-exit tile),
// software global barrier (all 512 blocks co-resident: 37.9KB LDS, <=128
// VGPR via launch_bounds -> 2 blocks/CU on 256 CUs), phase B = attn (R8
// deep-prefetch structure, one block per (b, o-pair)).
// ---------------------------------------------------------------------------
__global__ __launch_bounds__(512, 4) void fused_kernel(
    const float* __restrict__ q, const float* __restrict__ k,
    const float* __restrict__ v, const int* __restrict__ mask,
    const float* __restrict__ W1, const float* __restrict__ b1,
    const float* __restrict__ W2, const float* __restrict__ b2,
    const float* __restrict__ Wf, const float* __restrict__ bf,
    float* __restrict__ out, float* __restrict__ attn_out,
    float* __restrict__ Eq, float* __restrict__ Ek4, float* __restrict__ WfT,
    int* __restrict__ bar)
{
  __shared__ __align__(16) char SMEM[37888];

  const int t    = threadIdx.x;
  const int lane = t & 63;
  const int wid  = t >> 6;
  const int bx   = blockIdx.x;

  // ================= PHASE A: projections =================
  proj_tile(bx, SMEM, t, lane, wid, q, k, W1, b1, Wf, mask, Eq, Ek4, WfT);
  if (bx < 80) {
    __syncthreads();                  // LDS reuse between the two tiles
    proj_tile(512 + bx, SMEM, t, lane, wid, q, k, W1, b1, Wf, mask, Eq, Ek4, WfT);
  }

  // ---- software global barrier (single-use per launch; bar zeroed by
  // hipMemsetAsync in kernel_launch before this kernel) ----
  __syncthreads();
  __threadfence();                    // release phase-A writes
  if (t == 0) {
    __hip_atomic_fetch_add(bar, 1, __ATOMIC_ACQ_REL, __HIP_MEMORY_SCOPE_AGENT);
    while (__hip_atomic_load(bar, __ATOMIC_ACQUIRE, __HIP_MEMORY_SCOPE_AGENT) < NBLK) {
      __builtin_amdgcn_s_sleep(2);
    }
  }
  __syncthreads();
  __threadfence();                    // acquire side

  // ================= PHASE B: attention (R8 body) =================
  float* sc0  = (float*)(SMEM);             // [512]
  float* sc1  = (float*)(SMEM + 2048);      // [512]
  int*   idxs = (int*)(SMEM + 4096);        // [512]
  float* qs0  = (float*)(SMEM + 6144);      // [256]
  float* qs1  = (float*)(SMEM + 7168);      // [256]
  float* w2s  = (float*)(SMEM + 8192);      // [256]
  float* pvp  = (float*)(SMEM + 9216);      // [8][2][256]
  float* o0a  = (float*)(SMEM + 25600);     // [2][256]
  float* red4 = (float*)(SMEM + 27648);     // [8][2]
  float* redw = (float*)(SMEM + 27712);     // [8]
  int*   swt8 = (int*)(SMEM + 27744);       // [8]

  const int tile = (bx & 7) * 64 + (bx >> 3);   // XCD swizzle over 512
  const int b    = tile >> 5;
  const int bo0  = b * 64 + (tile & 31) * OT;

  // ---- inline mask scan ----
  const int unm = (mask[b * NI + t] == 0) ? 1 : 0;
  unsigned long long bal = __ballot(unm);
  int my = __popcll(bal & ((1ull << lane) - 1ull));
  if (lane == 0) swt8[wid] = __popcll(bal);

  // ---- stage Eq rows + W2 into LDS ----
  if (t < 128) {
    const int r = t >> 6, part = t & 63;
    float* dst = (r == 0) ? qs0 : qs1;
    *(float4*)&dst[part * 4] =
        *(const float4*)(Eq + (size_t)(bo0 + r) * DIM + part * 4);
  } else if (t < 192) {
    const int part = t - 128;
    *(float4*)&w2s[part * 4] = *(const float4*)(W2 + part * 4);
  }

  // ---- sumW2 ----
  float partial = (t < DIM) ? W2[t] : 0.f;
#pragma unroll
  for (int off = 32; off >= 1; off >>= 1) partial += __shfl_xor(partial, off, 64);
  if (lane == 0) redw[wid] = partial;
  __syncthreads();                               // B1

  int cntb = 0, woffv = 0;
#pragma unroll
  for (int w = 0; w < 8; ++w) {
    int v_ = swt8[w];
    if (w < wid) woffv += v_;
    cntb += v_;
  }
  const int myPos = unm ? (woffv + my) : -1;
  if (unm) idxs[myPos] = t;

  float sumw2 = 0.f;
#pragma unroll
  for (int w = 0; w < 8; ++w) sumw2 += redw[w];
  const float base = sumw2 + b2[0];

  // ---- phase 1: scores for compacted column j = t; 16-deep kq prefetch ----
  const int j = t;
  const bool active = (j < cntb);
  const int jc = active ? j : (cntb > 0 ? cntb - 1 : 0);
  const float4* kb4 = (const float4*)Ek4 + (size_t)b * 64 * NIP;

  float acc0 = 0.f, acc1 = 0.f;
  if (wid * 64 < cntb) {                 // wave-uniform skip of dead waves
    const float4* kp = kb4 + jc;
#pragma unroll
    for (int c0 = 0; c0 < 64; c0 += 16) {
      float4 kqr[16];
#pragma unroll
      for (int u = 0; u < 16; ++u)       // 16 independent loads in flight
        kqr[u] = kp[(size_t)(c0 + u) * NIP];
#pragma unroll
      for (int u = 0; u < 16; ++u) {
        const int hq = c0 + u;
        float wr[4], q0r[4], q1r[4], kv[4];
        f4arr(*(const float4*)&w2s[hq * 4], wr);
        f4arr(*(const float4*)&qs0[hq * 4], q0r);
        f4arr(*(const float4*)&qs1[hq * 4], q1r);
        f4arr(kqr[u], kv);
#pragma unroll
        for (int pr = 0; pr < 2; ++pr) {
          const int ea = pr * 2, eb = pr * 2 + 1;
          float A0 = fmaf(q0r[ea], kv[ea], 1.f);
          float B0 = fmaf(q0r[eb], kv[eb], 1.f);
          float N0 = fmaf(wr[eb], A0, wr[ea] * B0);
          acc0 = fmaf(N0, __builtin_amdgcn_rcpf(A0 * B0), acc0);
          float A1 = fmaf(q1r[ea], kv[ea], 1.f);
          float B1 = fmaf(q1r[eb], kv[eb], 1.f);
          float N1 = fmaf(wr[eb], A1, wr[ea] * B1);
          acc1 = fmaf(N1, __builtin_amdgcn_rcpf(A1 * B1), acc1);
        }
      }
    }
  }

  float s0 = active ? (base - 2.f * acc0) : -INFINITY;
  float s1 = active ? (base - 2.f * acc1) : -INFINITY;

  // ---- phase 2: softmax ----
  float p0 = __builtin_amdgcn_exp2f(s0 * 1.4426950408889634f);
  float p1 = __builtin_amdgcn_exp2f(s1 * 1.4426950408889634f);
  float ps0 = p0, ps1 = p1;
#pragma unroll
  for (int off = 32; off >= 1; off >>= 1) {
    ps0 += __shfl_xor(ps0, off, 64);
    ps1 += __shfl_xor(ps1, off, 64);
  }
  __syncthreads();
  if (lane == 0) { red4[wid * 2 + 0] = ps0; red4[wid * 2 + 1] = ps1; }
  __syncthreads();
  float ss0 = 0.f, ss1 = 0.f;
#pragma unroll
  for (int w = 0; w < 8; ++w) { ss0 += red4[w * 2 + 0]; ss1 += red4[w * 2 + 1]; }
  const float a0 = p0 * __builtin_amdgcn_rcpf(ss0);
  const float a1 = p1 * __builtin_amdgcn_rcpf(ss1);
  sc0[j] = a0;
  sc1[j] = a1;
  __syncthreads();

  // attn_out scatter-back
  {
    float w0 = (myPos >= 0) ? sc0[myPos] : 0.f;
    float w1 = (myPos >= 0) ? sc1[myPos] : 0.f;
    attn_out[(size_t)(bo0 + 0) * NI + t] = w0;
    attn_out[(size_t)(bo0 + 1) * NI + t] = w1;
  }

  // ---- phase 3: PV, 8-deep v-row prefetch ----
  {
    const int d4 = lane;
    float4 av0 = {0.f, 0.f, 0.f, 0.f};
    float4 av1 = {0.f, 0.f, 0.f, 0.f};
    const float4* vb4 = (const float4*)(v + (size_t)b * NI * DIM);
    const int jstart = wid * 64;
    const int jend = min(jstart + 64, cntb);
    int jb = jstart;
    for (; jb + 8 <= jend; jb += 8) {
      float4 vr[8];
      float sa0[8], sa1[8];
#pragma unroll
      for (int u = 0; u < 8; ++u) {
        int row = idxs[jb + u];
        vr[u] = vb4[(size_t)row * 64 + d4];
        sa0[u] = sc0[jb + u];
        sa1[u] = sc1[jb + u];
      }
#pragma unroll
      for (int u = 0; u < 8; ++u) {
        av0.x = fmaf(sa0[u], vr[u].x, av0.x);
        av0.y = fmaf(sa0[u], vr[u].y, av0.y);
        av0.z = fmaf(sa0[u], vr[u].z, av0.z);
        av0.w = fmaf(sa0[u], vr[u].w, av0.w);
        av1.x = fmaf(sa1[u], vr[u].x, av1.x);
        av1.y = fmaf(sa1[u], vr[u].y, av1.y);
        av1.z = fmaf(sa1[u], vr[u].z, av1.z);
        av1.w = fmaf(sa1[u], vr[u].w, av1.w);
      }
    }
    for (; jb < jend; ++jb) {
      int row = idxs[jb];
      float sa0 = sc0[jb], sa1 = sc1[jb];
      float4 vv = vb4[(size_t)row * 64 + d4];
      av0.x = fmaf(sa0, vv.x, av0.x);
      av0.y = fmaf(sa0, vv.y, av0.y);
      av0.z = fmaf(sa0, vv.z, av0.z);
      av0.w = fmaf(sa0, vv.w, av0.w);
      av1.x = fmaf(sa1, vv.x, av1.x);
      av1.y = fmaf(sa1, vv.y, av1.y);
      av1.z = fmaf(sa1, vv.z, av1.z);
      av1.w = fmaf(sa1, vv.w, av1.w);
    }
    *(float4*)&pvp[(wid * 2 + 0) * 256 + d4 * 4] = av0;
    *(float4*)&pvp[(wid * 2 + 1) * 256 + d4 * 4] = av1;
  }
  __syncthreads();
  {
    int oo = t >> 8, d = t & 255;
    float sacc = 0.f;
#pragma unroll
    for (int w = 0; w < 8; ++w) sacc += pvp[(w * 2 + oo) * 256 + d];
    o0a[oo * 256 + d] = sacc;
  }
  __syncthreads();

  // ---- phase 4: t<256 computes BOTH o's; 16-deep WfT prefetch ----
  if (t < DIM) {
    const int d = t;
    float f0 = 0.f, f1 = 0.f;
#pragma unroll
    for (int c0 = 0; c0 < 256; c0 += 16) {
      float wv[16];
#pragma unroll
      for (int u = 0; u < 16; ++u)
        wv[u] = WfT[(size_t)(c0 + u) * WFT_LD + d];
#pragma unroll
      for (int u = 0; u < 16; ++u) {
        f0 = fmaf(o0a[c0 + u], wv[u], f0);
        f1 = fmaf(o0a[256 + c0 + u], wv[u], f1);
      }
    }
    float bfv = bf[d];
    f0 += bfv; f1 += bfv;
    f0 = (f0 >= 0.f) ? f0 : NEG_SLOPE * f0;
    f1 = (f1 >= 0.f) ? f1 : NEG_SLOPE * f1;
    out[(size_t)(bo0 + 0) * DIM + d] = f0;
    out[(size_t)(bo0 + 1) * DIM + d] = f1;
  }
}

// ---------------------------------------------------------------------------
extern "C" void kernel_launch(void* const* d_in, const int* in_sizes, int n_in,
                              void* d_out, int out_size, void* d_ws, size_t ws_size,
                              hipStream_t stream) {
  const float* q    = (const float*)d_in[0];
  const float* k    = (const float*)d_in[1];
  const float* v    = (const float*)d_in[2];
  const int*   mask = (const int*)d_in[3];
  const float* W1   = (const float*)d_in[4];
  const float* b1   = (const float*)d_in[5];
  const float* W2   = (const float*)d_in[6];
  const float* b2   = (const float*)d_in[7];
  const float* Wf   = (const float*)d_in[8];
  const float* bf   = (const float*)d_in[9];

  float* out      = (float*)d_out;                    // (16,64,256)
  float* attn_out = out + (size_t)BATCH * NO * DIM;   // (16,64,512)

  float* Eq   = (float*)d_ws;                         // 1024 x 256
  float* Ek4  = Eq + (size_t)BATCH * NO * DIM;        // 16 x 64 x NIP x 4
  float* WfT  = Ek4 + (size_t)BATCH * 64 * NIP * 4;   // 256 x WFT_LD
  int*   bar  = (int*)(WfT + (size_t)DIM * WFT_LD);   // barrier counter

  hipMemsetAsync(bar, 0, 256, stream);                // reset barrier each launch
  fused_kernel<<<NBLK, 512, 0, stream>>>(q, k, v, mask, W1, b1, W2, b2, Wf, bf,
                                         out, attn_out, Eq, Ek4, WfT, bar);
}

// Round 12
// 122.649 us; speedup vs baseline: 2.8121x; 2.8121x over previous
//
#include <hip/hip_runtime.h>
#include <math.h>

#define DIM 256
#define BATCH 16
#define NO 64
#define NI 512
#define NIP 528                     // padded Ek4 inner extent (8448 B hq-stride)
#define WFT_LD 272                  // padded WfT row stride (1088 B)
#define NEG_SLOPE 0.01f
#define CSCALE 2.885390081777927f   // 2*log2(e): tanh(x) = 1 - 2/(exp2(CSCALE*x)+1)
#define OT 2                        // o's per attn block

typedef float f32x4 __attribute__((ext_vector_type(4)));
typedef __bf16 bf16x8 __attribute__((ext_vector_type(8)));
typedef unsigned int u32x4 __attribute__((ext_vector_type(4)));

// ---------------------------------------------------------------------------
// split f32 -> bf16 hi (RNE, returned as low-16 bits) + exact f32 residual
// ---------------------------------------------------------------------------
__device__ __forceinline__ void split2(float f, unsigned int& hi16, float& lo) {
  unsigned int u = __builtin_bit_cast(unsigned int, f);
  unsigned int h = (u + 0x7FFFu + ((u >> 16) & 1u)) & 0xFFFF0000u; // RNE bf16, as f32 bits
  hi16 = h >> 16;
  lo = f - __builtin_bit_cast(float, h);   // exact (Sterbenz)
}
__device__ __forceinline__ unsigned int rne16(float f) {
  unsigned int u = __builtin_bit_cast(unsigned int, f);
  return (u + 0x7FFFu + ((u >> 16) & 1u)) >> 16;
}

struct __align__(8) U2 { unsigned int x, y; };

// ---------------------------------------------------------------------------
// Kernel 1 (blocks 0..575): GEMM  out[r,h] = sum_d A[r,d] * W1[h, coff+d]
// via split-bf16 3-pass MFMA (AhWh + AhWl + AlWh), fp32 accumulate.
//   blocks 0..63   (q): Eq[bo][h] = exp2(CSCALE*(acc + b1[h]))
//   blocks 64..575 (k): MASK-COMPACTED GEMM (inline ballot-prefix mask scan;
//     block owns compacted slots [jb0, jb0+64), exits if jb0 >= cnt[b]).
// 64x64 tile, 4 waves (2x2 grid of 32x32 wave-tiles), K-chunk 64.
// Blocks 576..591: Wf -> WfT transpose (padded row stride WFT_LD).
// ---------------------------------------------------------------------------
#define OFF_AH 0
#define OFF_AL 9216
#define OFF_WH 18432
#define OFF_WL 27648

__global__ __launch_bounds__(256, 4) void proj_kernel(
    const float* __restrict__ q, const float* __restrict__ k,
    const float* __restrict__ W1, const float* __restrict__ b1,
    const float* __restrict__ Wf, const int* __restrict__ mask,
    float* __restrict__ Eq, float* __restrict__ Ek4, float* __restrict__ WfT)
{
  __shared__ __align__(16) char smemRaw[36864];   // 36 KB
  __shared__ int idx_s[64];                       // gather window
  __shared__ int swtot[4];

  const int t  = threadIdx.x;
  const int bx = blockIdx.x;

  if (bx >= 576) {                 // ---- Wf transpose path ----
    float* smem = (float*)smemRaw;
    const int tt = bx - 576;
    const int tr = tt >> 2, tc = tt & 3;
#pragma unroll
    for (int p = 0; p < 4; ++p) {
      int idx2 = p * 256 + t;
      int row = idx2 >> 4, j = idx2 & 15;
      float4 vv = *(const float4*)(Wf + (size_t)(tr * 64 + row) * 256 + tc * 64 + j * 4);
      *(float4*)&smem[row * 68 + j * 4] = vv;
    }
    __syncthreads();
#pragma unroll
    for (int p = 0; p < 4; ++p) {
      int idx2 = p * 256 + t;
      int row = idx2 >> 4, j = idx2 & 15;
      float4 ov;
      ov.x = smem[(j * 4 + 0) * 68 + row];
      ov.y = smem[(j * 4 + 1) * 68 + row];
      ov.z = smem[(j * 4 + 2) * 68 + row];
      ov.w = smem[(j * 4 + 3) * 68 + row];
      *(float4*)(WfT + (size_t)(tc * 64 + row) * WFT_LD + tr * 64 + j * 4) = ov;
    }
    return;
  }

  const int mt = bx >> 2;
  const int nt = bx & 3;
  const int h0 = nt * 64;
  const bool isq = (mt < 16);

  const int srow = t >> 4;           // staging rows: srow + {0,16,32,48}
  const int sc4  = t & 15;
  const int lane = t & 63, w = t >> 6;
  const int m0w = (w >> 1) * 32, n0w = (w & 1) * 32;
  const int lr = lane & 15, lg = lane >> 4;

  const float* src;
  int coff, bb = 0, jb0 = 0, cntb = 0;
  int rowg[4];

  if (isq) {
    src  = q + (size_t)(mt * 64) * DIM;
    coff = 0;
#pragma unroll
    for (int p = 0; p < 4; ++p) rowg[p] = srow + p * 16;
  } else {
    const int ki = mt - 16;          // 0..127
    bb  = ki >> 3;                   // batch
    jb0 = (ki & 7) * 64;             // compacted window start
    // ---- inline mask scan: thread t handles entries 2t, 2t+1 ----
    const int e0 = (mask[bb * NI + 2 * t] == 0);
    const int e1 = (mask[bb * NI + 2 * t + 1] == 0);
    const int ps = e0 + e1;
    int x = ps;
#pragma unroll
    for (int off = 1; off < 64; off <<= 1) {
      int y = __shfl_up(x, off, 64);
      if (lane >= off) x += y;
    }
    if (lane == 63) swtot[w] = x;
    if (t < 64) idx_s[t] = 0;        // safe default for tail rows
    __syncthreads();
    int woffv = 0;
#pragma unroll
    for (int w2 = 0; w2 < 4; ++w2) {
      int v_ = swtot[w2];
      if (w2 < w) woffv += v_;
      cntb += v_;
    }
    const int excl = woffv + x - ps;          // prefix before entry 2t
    const int p0 = excl, p1 = excl + e0;
    if (e0 && p0 >= jb0 && p0 < jb0 + 64) idx_s[p0 - jb0] = 2 * t;
    if (e1 && p1 >= jb0 && p1 < jb0 + 64) idx_s[p1 - jb0] = 2 * t + 1;
    __syncthreads();
    if (jb0 >= cntb) return;         // block-uniform: nothing to do
    src  = k + (size_t)bb * NI * DIM;
    coff = DIM;
#pragma unroll
    for (int p = 0; p < 4; ++p) rowg[p] = idx_s[srow + p * 16];
  }

  f32x4 acc[2][2] = {};

  float4 aR[4], wR[4];
#define LOADC(c0_)                                                              \
  _Pragma("unroll")                                                             \
  for (int p = 0; p < 4; ++p) {                                                 \
    aR[p] = *(const float4*)(src + (size_t)rowg[p] * DIM + (c0_) + sc4 * 4);    \
    wR[p] = *(const float4*)(W1 + (size_t)(h0 + srow + p * 16) * (2 * DIM) + coff + (c0_) + sc4 * 4); \
  }

  LOADC(0)

  for (int c = 0; c < 4; ++c) {
    // ---- convert chunk c (in regs) to bf16 hi/lo and stage to LDS ----
#pragma unroll
    for (int p = 0; p < 4; ++p) {
      int row = srow + p * 16;
      int boff = row * 144 + sc4 * 8;     // byte offset within each array
      unsigned int h0_, h1_, h2_, h3_;
      float l0, l1, l2, l3;
      split2(aR[p].x, h0_, l0); split2(aR[p].y, h1_, l1);
      split2(aR[p].z, h2_, l2); split2(aR[p].w, h3_, l3);
      *(U2*)(smemRaw + OFF_AH + boff) = { h0_ | (h1_ << 16), h2_ | (h3_ << 16) };
      *(U2*)(smemRaw + OFF_AL + boff) = { rne16(l0) | (rne16(l1) << 16),
                                          rne16(l2) | (rne16(l3) << 16) };
      split2(wR[p].x, h0_, l0); split2(wR[p].y, h1_, l1);
      split2(wR[p].z, h2_, l2); split2(wR[p].w, h3_, l3);
      *(U2*)(smemRaw + OFF_WH + boff) = { h0_ | (h1_ << 16), h2_ | (h3_ << 16) };
      *(U2*)(smemRaw + OFF_WL + boff) = { rne16(l0) | (rne16(l1) << 16),
                                          rne16(l2) | (rne16(l3) << 16) };
    }
    __syncthreads();

    if (c < 3) { LOADC((c + 1) * 64) }   // issue-early: flies under the MFMAs

    // ---- MFMA over this 64-wide K chunk: 2 k-steps of 32 ----
#pragma unroll
    for (int kk = 0; kk < 2; ++kk) {
      const int kb = kk * 64 + lg * 16;  // byte offset of this lane's 8 bf16
      bf16x8 ah[2], al[2], bh[2], bl[2];
#pragma unroll
      for (int mi = 0; mi < 2; ++mi) {
        int row = m0w + mi * 16 + lr;
        ah[mi] = __builtin_bit_cast(bf16x8, *(const u32x4*)(smemRaw + OFF_AH + row * 144 + kb));
        al[mi] = __builtin_bit_cast(bf16x8, *(const u32x4*)(smemRaw + OFF_AL + row * 144 + kb));
      }
#pragma unroll
      for (int ni = 0; ni < 2; ++ni) {
        int row = n0w + ni * 16 + lr;
        bh[ni] = __builtin_bit_cast(bf16x8, *(const u32x4*)(smemRaw + OFF_WH + row * 144 + kb));
        bl[ni] = __builtin_bit_cast(bf16x8, *(const u32x4*)(smemRaw + OFF_WL + row * 144 + kb));
      }
#pragma unroll
      for (int mi = 0; mi < 2; ++mi)
#pragma unroll
        for (int ni = 0; ni < 2; ++ni) {
          acc[mi][ni] = __builtin_amdgcn_mfma_f32_16x16x32_bf16(ah[mi], bh[ni], acc[mi][ni], 0, 0, 0);
          acc[mi][ni] = __builtin_amdgcn_mfma_f32_16x16x32_bf16(ah[mi], bl[ni], acc[mi][ni], 0, 0, 0);
          acc[mi][ni] = __builtin_amdgcn_mfma_f32_16x16x32_bf16(al[mi], bh[ni], acc[mi][ni], 0, 0, 0);
        }
    }
    __syncthreads();
  }

  // ---- epilogue. C/D layout (m89-verified): col(n)=lane&15, row(m)=(lane>>4)*4+reg
  if (isq) {
    const int r0 = mt * 64;
#pragma unroll
    for (int ni = 0; ni < 2; ++ni) {
      int h = h0 + n0w + ni * 16 + lr;
      float b1v = b1[h];
#pragma unroll
      for (int mi = 0; mi < 2; ++mi)
#pragma unroll
        for (int rg = 0; rg < 4; ++rg) {
          int r = r0 + m0w + mi * 16 + lg * 4 + rg;
          Eq[(size_t)r * DIM + h] =
              __builtin_amdgcn_exp2f((acc[mi][ni][rg] + b1v) * CSCALE);
        }
    }
  } else {
    const int lim = cntb - jb0;      // valid local rows in this window
#pragma unroll
    for (int mi = 0; mi < 2; ++mi)
#pragma unroll
      for (int rg = 0; rg < 4; ++rg) {
        int local = m0w + mi * 16 + lg * 4 + rg;
        if (local < lim) {
          int pos = jb0 + local;     // dense compacted slot
#pragma unroll
          for (int ni = 0; ni < 2; ++ni) {
            int h = h0 + n0w + ni * 16 + lr;
            Ek4[((size_t)(bb * 64 + (h >> 2)) * NIP + pos) * 4 + (h & 3)] =
                __builtin_amdgcn_exp2f(acc[mi][ni][rg] * CSCALE);
          }
        }
      }
  }
}

__device__ __forceinline__ void f4arr(float4 v, float* a) {
  a[0] = v.x; a[1] = v.y; a[2] = v.z; a[3] = v.w;
}

// ---------------------------------------------------------------------------
// Kernel 2: one block (512 threads) per (b, o-pair). Grid 512. XCD-swizzled.
// Deep-prefetch structure: phases 1/3/4 batch 16/8/16 loads into register
// arrays before consuming. Eq/W2 staged in LDS.
// ---------------------------------------------------------------------------
__global__ __launch_bounds__(512, 4) void attn_kernel(
    const float* __restrict__ Eq, const float* __restrict__ Ek4,
    const float* __restrict__ v, const int* __restrict__ mask,
    const float* __restrict__ W2, const float* __restrict__ b2,
    const float* __restrict__ WfT, const float* __restrict__ bf,
    float* __restrict__ out, float* __restrict__ attn_out)
{
  __shared__ float sc[OT][NI];        // 4 KB (compacted attn weights)
  __shared__ int   idxs[NI];          // 2 KB
  __shared__ float qs[OT][DIM];       // 2 KB
  __shared__ float w2s[DIM];          // 1 KB
  __shared__ float pvp[8][OT][DIM];   // 16 KB
  __shared__ float o0[OT][DIM];       // 2 KB
  __shared__ float red4[8][OT];
  __shared__ float redw[8];
  __shared__ int   swtot8[8];

  const int t    = threadIdx.x;
  const int lane = t & 63;
  const int wid  = t >> 6;

  const int blk  = blockIdx.x;
  const int tile = (blk & 7) * 64 + (blk >> 3);   // XCD swizzle
  const int b    = tile >> 5;
  const int bo0  = b * 64 + (tile & 31) * OT;

  // ---- inline mask scan ----
  const int unm = (mask[b * NI + t] == 0) ? 1 : 0;
  unsigned long long bal = __ballot(unm);
  int my = __popcll(bal & ((1ull << lane) - 1ull));
  if (lane == 0) swtot8[wid] = __popcll(bal);

  // ---- stage Eq rows + W2 into LDS (disjoint thread groups) ----
  if (t < 128) {
    const int r = t >> 6, part = t & 63;
    *(float4*)&qs[r][part * 4] =
        *(const float4*)(Eq + (size_t)(bo0 + r) * DIM + part * 4);
  } else if (t < 192) {
    const int part = t - 128;
    *(float4*)&w2s[part * 4] = *(const float4*)(W2 + part * 4);
  }

  // ---- sumW2 ----
  float partial = (t < DIM) ? W2[t] : 0.f;
#pragma unroll
  for (int off = 32; off >= 1; off >>= 1) partial += __shfl_xor(partial, off, 64);
  if (lane == 0) redw[wid] = partial;
  __syncthreads();                               // B1

  int cntb = 0, woffv = 0;
#pragma unroll
  for (int w = 0; w < 8; ++w) {
    int v_ = swtot8[w];
    if (w < wid) woffv += v_;
    cntb += v_;
  }
  const int myPos = unm ? (woffv + my) : -1;
  if (unm) idxs[myPos] = t;          // read in phase 3, after barriers

  float sumw2 = 0.f;
#pragma unroll
  for (int w = 0; w < 8; ++w) sumw2 += redw[w];
  const float base = sumw2 + b2[0];

  // ---- phase 1: scores for compacted column j = t; 16-deep kq prefetch ----
  const int j = t;
  const bool active = (j < cntb);
  const int jc = active ? j : (cntb > 0 ? cntb - 1 : 0);   // clamped safe index
  const float4* kb4 = (const float4*)Ek4 + (size_t)b * 64 * NIP;  // [hq*NIP + j]

  float acc0 = 0.f, acc1 = 0.f;
  if (wid * 64 < cntb) {                 // wave-uniform skip of dead waves
    const float4* kp = kb4 + jc;
#pragma unroll
    for (int c0 = 0; c0 < 64; c0 += 16) {
      float4 kqr[16];
#pragma unroll
      for (int u = 0; u < 16; ++u)       // 16 independent loads in flight
        kqr[u] = kp[(size_t)(c0 + u) * NIP];
#pragma unroll
      for (int u = 0; u < 16; ++u) {
        const int hq = c0 + u;
        float wr[4], q0r[4], q1r[4], kv[4];
        f4arr(*(const float4*)&w2s[hq * 4], wr);       // LDS broadcast
        f4arr(*(const float4*)&qs[0][hq * 4], q0r);
        f4arr(*(const float4*)&qs[1][hq * 4], q1r);
        f4arr(kqr[u], kv);
#pragma unroll
        for (int pr = 0; pr < 2; ++pr) {               // pairs (0,1), (2,3)
          const int ea = pr * 2, eb = pr * 2 + 1;
          float A0 = fmaf(q0r[ea], kv[ea], 1.f);
          float B0 = fmaf(q0r[eb], kv[eb], 1.f);
          float N0 = fmaf(wr[eb], A0, wr[ea] * B0);
          acc0 = fmaf(N0, __builtin_amdgcn_rcpf(A0 * B0), acc0);
          float A1 = fmaf(q1r[ea], kv[ea], 1.f);
          float B1 = fmaf(q1r[eb], kv[eb], 1.f);
          float N1 = fmaf(wr[eb], A1, wr[ea] * B1);
          acc1 = fmaf(N1, __builtin_amdgcn_rcpf(A1 * B1), acc1);
        }
      }
    }
  }

  float s0 = active ? (base - 2.f * acc0) : -INFINITY;
  float s1 = active ? (base - 2.f * acc1) : -INFINITY;

  // ---- phase 2: softmax over compacted set, no max-subtraction ----
  float p0 = __builtin_amdgcn_exp2f(s0 * 1.4426950408889634f);
  float p1 = __builtin_amdgcn_exp2f(s1 * 1.4426950408889634f);
  float ps0 = p0, ps1 = p1;
#pragma unroll
  for (int off = 32; off >= 1; off >>= 1) {
    ps0 += __shfl_xor(ps0, off, 64);
    ps1 += __shfl_xor(ps1, off, 64);
  }
  __syncthreads();               // redw reads done; red4 safe
  if (lane == 0) { red4[wid][0] = ps0; red4[wid][1] = ps1; }
  __syncthreads();
  float ss0 = 0.f, ss1 = 0.f;
#pragma unroll
  for (int w = 0; w < 8; ++w) { ss0 += red4[w][0]; ss1 += red4[w][1]; }
  const float a0 = p0 * __builtin_amdgcn_rcpf(ss0);
  const float a1 = p1 * __builtin_amdgcn_rcpf(ss1);
  sc[0][j] = a0;                 // compacted slot (0 for inactive j)
  sc[1][j] = a1;
  __syncthreads();

  // attn_out scatter-back: original column i = t; masked -> exact 0
  {
    float w0 = (myPos >= 0) ? sc[0][myPos] : 0.f;
    float w1 = (myPos >= 0) ? sc[1][myPos] : 0.f;
    attn_out[(size_t)(bo0 + 0) * NI + t] = w0;
    attn_out[(size_t)(bo0 + 1) * NI + t] = w1;
  }

  // ---- phase 3: PV, 8-deep v-row prefetch. wave wid: j in [wid*64,+64) ----
  {
    const int d4 = lane;
    float4 av0 = {0.f, 0.f, 0.f, 0.f};
    float4 av1 = {0.f, 0.f, 0.f, 0.f};
    const float4* vb4 = (const float4*)(v + (size_t)b * NI * DIM);
    const int jstart = wid * 64;
    const int jend = min(jstart + 64, cntb);
    int jb = jstart;
    for (; jb + 8 <= jend; jb += 8) {
      float4 vr[8];
      float sa0[8], sa1[8];
#pragma unroll
      for (int u = 0; u < 8; ++u) {
        int row = idxs[jb + u];                  // LDS (fast)
        vr[u] = vb4[(size_t)row * 64 + d4];      // 8 loads in flight
        sa0[u] = sc[0][jb + u];
        sa1[u] = sc[1][jb + u];
      }
#pragma unroll
      for (int u = 0; u < 8; ++u) {
        av0.x = fmaf(sa0[u], vr[u].x, av0.x);
        av0.y = fmaf(sa0[u], vr[u].y, av0.y);
        av0.z = fmaf(sa0[u], vr[u].z, av0.z);
        av0.w = fmaf(sa0[u], vr[u].w, av0.w);
        av1.x = fmaf(sa1[u], vr[u].x, av1.x);
        av1.y = fmaf(sa1[u], vr[u].y, av1.y);
        av1.z = fmaf(sa1[u], vr[u].z, av1.z);
        av1.w = fmaf(sa1[u], vr[u].w, av1.w);
      }
    }
    for (; jb < jend; ++jb) {                    // tail
      int row = idxs[jb];
      float sa0 = sc[0][jb], sa1 = sc[1][jb];
      float4 vv = vb4[(size_t)row * 64 + d4];
      av0.x = fmaf(sa0, vv.x, av0.x);
      av0.y = fmaf(sa0, vv.y, av0.y);
      av0.z = fmaf(sa0, vv.z, av0.z);
      av0.w = fmaf(sa0, vv.w, av0.w);
      av1.x = fmaf(sa1, vv.x, av1.x);
      av1.y = fmaf(sa1, vv.y, av1.y);
      av1.z = fmaf(sa1, vv.z, av1.z);
      av1.w = fmaf(sa1, vv.w, av1.w);
    }
    *(float4*)&pvp[wid][0][d4 * 4] = av0;        // dead waves store zeros
    *(float4*)&pvp[wid][1][d4 * 4] = av1;
  }
  __syncthreads();
  {
    int oo = t >> 8, d = t & 255;
    float sacc = 0.f;
#pragma unroll
    for (int w = 0; w < 8; ++w) sacc += pvp[w][oo][d];
    o0[oo][d] = sacc;
  }
  __syncthreads();

  // ---- phase 4: t<256 computes BOTH o's; 16-deep WfT prefetch ----
  if (t < DIM) {
    const int d = t;
    float f0 = 0.f, f1 = 0.f;
#pragma unroll
    for (int c0 = 0; c0 < 256; c0 += 16) {
      float wv[16];
#pragma unroll
      for (int u = 0; u < 16; ++u)               // 16 loads in flight
        wv[u] = WfT[(size_t)(c0 + u) * WFT_LD + d];
#pragma unroll
      for (int u = 0; u < 16; ++u) {
        f0 = fmaf(o0[0][c0 + u], wv[u], f0);
        f1 = fmaf(o0[1][c0 + u], wv[u], f1);
      }
    }
    float bfv = bf[d];
    f0 += bfv; f1 += bfv;
    f0 = (f0 >= 0.f) ? f0 : NEG_SLOPE * f0;
    f1 = (f1 >= 0.f) ? f1 : NEG_SLOPE * f1;
    out[(size_t)(bo0 + 0) * DIM + d] = f0;
    out[(size_t)(bo0 + 1) * DIM + d] = f1;
  }
}

// ---------------------------------------------------------------------------
extern "C" void kernel_launch(void* const* d_in, const int* in_sizes, int n_in,
                              void* d_out, int out_size, void* d_ws, size_t ws_size,
                              hipStream_t stream) {
  const float* q    = (const float*)d_in[0];
  const float* k    = (const float*)d_in[1];
  const float* v    = (const float*)d_in[2];
  const int*   mask = (const int*)d_in[3];
  const float* W1   = (const float*)d_in[4];
  const float* b1   = (const float*)d_in[5];
  const float* W2   = (const float*)d_in[6];
  const float* b2   = (const float*)d_in[7];
  const float* Wf   = (const float*)d_in[8];
  const float* bf   = (const float*)d_in[9];

  float* out      = (float*)d_out;                    // (16,64,256)
  float* attn_out = out + (size_t)BATCH * NO * DIM;   // (16,64,512)

  float* Eq   = (float*)d_ws;                         // 1024 x 256
  float* Ek4  = Eq + (size_t)BATCH * NO * DIM;        // 16 x 64 x NIP x 4
  float* WfT  = Ek4 + (size_t)BATCH * 64 * NIP * 4;   // 256 x WFT_LD

  proj_kernel<<<592, 256, 0, stream>>>(q, k, W1, b1, Wf, mask, Eq, Ek4, WfT);
  attn_kernel<<<(BATCH * NO) / OT, 512, 0, stream>>>(Eq, Ek4, v, mask,
                                                     W2, b2, WfT, bf, out, attn_out);
}